// Round 5
// baseline (48.102 us; speedup 1.0000x reference)
//
#include <hip/hip_runtime.h>
#include <math.h>

#define N_NODES 30000
#define K_NBR   16
#define C_IN    256
#define C_OUT   128
#define KS      9
#define S_MB    17

typedef __attribute__((ext_vector_type(4))) float f32x4;
typedef __attribute__((ext_vector_type(2))) float f32x2;
typedef __attribute__((ext_vector_type(8))) short bf16x8;

static __device__ __forceinline__ ushort f2bf(float f) {
    uint u = __builtin_bit_cast(uint, f);
    u += 0x7fffu + ((u >> 16) & 1u);          // round-to-nearest-even
    return (ushort)(u >> 16);
}

// ---------------------------------------------------------------------------
// Prep: blocks 0..31 convert stacked W (rows 0..127 = W_lin, 128..255 = W_res)
// into fragment-ordered bf16 Bf (frag f = kc*16+colhi; lane l: col_lo=l&15,
// ksub=l>>4; 8 bf16 each). Block 32 computes per-channel constants Ws/Cd.
// ---------------------------------------------------------------------------
__global__ __launch_bounds__(256)
void pcg_prep(const float* __restrict__ W_lin,
              const float* __restrict__ W_res,
              const float* __restrict__ weight,
              const float* __restrict__ b_lin,
              const float* __restrict__ bias,
              const float* __restrict__ b_res,
              ushort* __restrict__ Bf,
              float* __restrict__ Ws,
              float* __restrict__ Cd) {
    if (blockIdx.x == 32) {
        int d = threadIdx.x;
        if (d >= C_OUT) return;
        float freq = powf(10000.0f, -(float)(d & ~1) / (float)C_OUT);
        float ws = 0.f, p = 0.f;
        for (int s = 0; s < S_MB; ++s) {
            int idx = (int)floorf((float)s * (9.0f / 17.0f));
            ws += weight[d * KS + idx];
            float ang = (float)idx * freq;
            p += (d & 1) ? cosf(ang) : sinf(ang);
        }
        Ws[d] = ws;
        Cd[d] = ws * ((float)(K_NBR + 1) * b_lin[d] + p) + bias[d] + b_res[d];
        return;
    }
    const int tt     = blockIdx.x * 256 + threadIdx.x;   // 0..8191
    const int col_lo = tt & 15;
    const int ksub   = (tt >> 4) & 3;
    const int colhi  = (tt >> 6) & 15;
    const int kc     = tt >> 10;
    const int col    = colhi * 16 + col_lo;
    const int k0     = kc * 32 + ksub * 8;
    const float* Wr = (col < C_OUT)
        ? &W_lin[(size_t)col * C_IN + k0]
        : &W_res[(size_t)(col - C_OUT) * C_IN + k0];
    const f32x4 w0 = *reinterpret_cast<const f32x4*>(Wr);
    const f32x4 w1 = *reinterpret_cast<const f32x4*>(Wr + 4);
    ushort b[8] = { f2bf(w0.x), f2bf(w0.y), f2bf(w0.z), f2bf(w0.w),
                    f2bf(w1.x), f2bf(w1.y), f2bf(w1.z), f2bf(w1.w) };
    *reinterpret_cast<uint4*>(&Bf[(size_t)tt * 8]) =
        *reinterpret_cast<const uint4*>(b);
}

// ---------------------------------------------------------------------------
// MFMA GEMM + full epilogue fold:
//   G[n][d] = ndata[n,:].W_lin[d,:],  R[n][d] = ndata[n,:].W_res[d,:]
//   Gs[n][d] = Ws[d]*G   (bf16 — the gathered operand)
//   Pc[n][d] = Ws[d]*G + R + Cd[d]  (bf16 — complete non-neighbor part)
// Block: 64 rows x (128 G-cols + 128 R-cols), 4 waves.
// Wave w computes G cols w*32..w*32+31 (cg 0,1) AND R cols for the SAME d
// (cg 2,3) so Gs/Pc combine in-register.
// ---------------------------------------------------------------------------
__global__ __launch_bounds__(256)
void pcg_mfma(const float* __restrict__ ndata,
              const ushort* __restrict__ Bf,
              const float* __restrict__ Ws,
              const float* __restrict__ Cd,
              ushort* __restrict__ Gs,
              ushort* __restrict__ Pc) {
    __shared__ short sA[16384];                // 64 rows x 256 k, bf16, 32 KB

    const int t  = threadIdx.x;
    const int n0 = blockIdx.x * 64;

    // ---- stage A tile (f32 -> bf16, fragment-lane order) ----
#pragma unroll
    for (int i = 0; i < 16; ++i) {
        const int v    = i * 256 + t;          // float4 index within 64x256 tile
        const int row  = v >> 6;
        const int k0   = (v & 63) * 4;
        f32x4 a = {0.f, 0.f, 0.f, 0.f};
        if (n0 + row < N_NODES)
            a = __builtin_nontemporal_load(reinterpret_cast<const f32x4*>(
                    &ndata[(size_t)(n0 + row) * C_IN + k0]));
        const int kc   = k0 >> 5;
        const int rg   = row >> 4;
        const int l    = (row & 15) | (((k0 >> 3) & 3) << 4);
        const int half = (k0 >> 2) & 1;
        uint2 w;
        w.x = (uint)f2bf(a.x) | ((uint)f2bf(a.y) << 16);
        w.y = (uint)f2bf(a.z) | ((uint)f2bf(a.w) << 16);
        *reinterpret_cast<uint2*>(&sA[(kc * 4 + rg) * 512 + l * 8 + half * 4]) = w;
    }
    __syncthreads();

    const int wave = t >> 6;
    const int l    = t & 63;

    // column-group -> stacked-column-high mapping (G,G,R,R for same d range)
    const int ch0 = 2 * wave;        // G cols wave*32 +  0..15
    const int ch1 = 2 * wave + 1;    // G cols wave*32 + 16..31
    const int ch2 = 8 + 2 * wave;    // R cols (same d)
    const int ch3 = 9 + 2 * wave;

    f32x4 acc[4][4] = {};                       // [rg][cg]

#pragma unroll
    for (int kc = 0; kc < 8; ++kc) {
        bf16x8 a[4];
#pragma unroll
        for (int rg = 0; rg < 4; ++rg)
            a[rg] = *reinterpret_cast<const bf16x8*>(
                        &sA[(kc * 4 + rg) * 512 + l * 8]);
        bf16x8 b[4];
        b[0] = *reinterpret_cast<const bf16x8*>(&Bf[((size_t)(kc * 16 + ch0) * 64 + l) * 8]);
        b[1] = *reinterpret_cast<const bf16x8*>(&Bf[((size_t)(kc * 16 + ch1) * 64 + l) * 8]);
        b[2] = *reinterpret_cast<const bf16x8*>(&Bf[((size_t)(kc * 16 + ch2) * 64 + l) * 8]);
        b[3] = *reinterpret_cast<const bf16x8*>(&Bf[((size_t)(kc * 16 + ch3) * 64 + l) * 8]);
#pragma unroll
        for (int rg = 0; rg < 4; ++rg)
#pragma unroll
            for (int cg = 0; cg < 4; ++cg)
                acc[rg][cg] = __builtin_amdgcn_mfma_f32_16x16x32_bf16(
                                  a[rg], b[cg], acc[rg][cg], 0, 0, 0);
    }

    // ---- epilogue: D layout col = lane&15, row = (lane>>4)*4 + reg ----
    const int cl  = l & 15;
    const int c0  = wave * 32 + cl;            // G col for cg 0 / R cg 2
    const int c1  = wave * 32 + 16 + cl;       // G col for cg 1 / R cg 3
    const float ws0 = Ws[c0], ws1 = Ws[c1];
    const float cd0 = Cd[c0], cd1 = Cd[c1];
    const int rl  = (l >> 4) * 4;
#pragma unroll
    for (int rg = 0; rg < 4; ++rg) {
#pragma unroll
        for (int j = 0; j < 4; ++j) {
            const int row = n0 + rg * 16 + rl + j;
            if (row < N_NODES) {
                const float gs0 = ws0 * acc[rg][0][j];
                const float gs1 = ws1 * acc[rg][1][j];
                Gs[(size_t)row * C_OUT + c0] = f2bf(gs0);
                Gs[(size_t)row * C_OUT + c1] = f2bf(gs1);
                Pc[(size_t)row * C_OUT + c0] = f2bf(gs0 + acc[rg][2][j] + cd0);
                Pc[(size_t)row * C_OUT + c1] = f2bf(gs1 + acc[rg][3][j] + cd1);
            }
        }
    }
}

// ---------------------------------------------------------------------------
// Gather: out[n][d] = Pc[n][d] + sum_k Gs[neighbors[n,k]][d]
// 4 nodes per 256-thread block; lane (64/node) covers cols 2l, 2l+1.
// ---------------------------------------------------------------------------
__global__ __launch_bounds__(256)
void pcg_gather(const int* __restrict__ neighbors,
                const ushort* __restrict__ Gs,
                const ushort* __restrict__ Pc,
                float* __restrict__ out) {
    __shared__ int snb[64];
    const int t = threadIdx.x;
    if (t < 64) snb[t] = neighbors[(size_t)blockIdx.x * 64 + t];
    __syncthreads();

    const int g = t >> 6;                      // node group 0..3
    const int l = t & 63;
    const int n = blockIdx.x * 4 + g;

    uint p = *reinterpret_cast<const uint*>(&Pc[(size_t)n * C_OUT + 2 * l]);
    float a0 = __builtin_bit_cast(float, p << 16);
    float a1 = __builtin_bit_cast(float, p & 0xffff0000u);

#pragma unroll
    for (int k = 0; k < K_NBR; ++k) {
        const int m = snb[g * 16 + k];
        uint v = *reinterpret_cast<const uint*>(&Gs[(size_t)m * C_OUT + 2 * l]);
        a0 += __builtin_bit_cast(float, v << 16);
        a1 += __builtin_bit_cast(float, v & 0xffff0000u);
    }

    f32x2 o = {a0, a1};
    __builtin_nontemporal_store(o, reinterpret_cast<f32x2*>(
        &out[(size_t)n * C_OUT + 2 * l]));
}

// ---------------------------------------------------------------------------
extern "C" void kernel_launch(void* const* d_in, const int* in_sizes, int n_in,
                              void* d_out, int out_size, void* d_ws, size_t ws_size,
                              hipStream_t stream) {
    const float* ndata     = (const float*)d_in[0];
    const int*   neighbors = (const int*)  d_in[1];
    const float* W_lin     = (const float*)d_in[2];
    const float* b_lin     = (const float*)d_in[3];
    const float* weight    = (const float*)d_in[4];
    const float* bias      = (const float*)d_in[5];
    const float* W_res     = (const float*)d_in[6];
    const float* b_res     = (const float*)d_in[7];
    float* out = (float*)d_out;

    ushort* Bf = (ushort*)d_ws;                          // [8192][8] = 128 KB
    ushort* Gq = Bf + 65536;                             // Gs [N][128] = 7.68 MB
    ushort* Pq = Gq + (size_t)N_NODES * C_OUT;           // Pc [N][128] = 7.68 MB
    float*  Ws = (float*)(Pq + (size_t)N_NODES * C_OUT); // [128]
    float*  Cd = Ws + C_OUT;                             // [128]

    pcg_prep<<<33, 256, 0, stream>>>(W_lin, W_res, weight, b_lin, bias, b_res,
                                     Bf, Ws, Cd);
    pcg_mfma<<<(N_NODES + 63) / 64, 256, 0, stream>>>(ndata, Bf, Ws, Cd, Gq, Pq);
    pcg_gather<<<N_NODES / 4, 256, 0, stream>>>(neighbors, Gq, Pq, out);
}

// Round 6
// 43.134 us; speedup vs baseline: 1.1152x; 1.1152x over previous
//
#include <hip/hip_runtime.h>
#include <math.h>

#define N_NODES 30000
#define K_NBR   16
#define C_IN    256
#define C_OUT   128
#define KS      9
#define S_MB    17

typedef __attribute__((ext_vector_type(4))) float f32x4;
typedef __attribute__((ext_vector_type(2))) float f32x2;
typedef __attribute__((ext_vector_type(8))) short bf16x8;

static __device__ __forceinline__ ushort f2bf(float f) {
    uint u = __builtin_bit_cast(uint, f);
    u += 0x7fffu + ((u >> 16) & 1u);          // round-to-nearest-even
    return (ushort)(u >> 16);
}

// ---------------------------------------------------------------------------
// Prep: blocks 0..31 convert stacked W (rows 0..127 = W_lin, 128..255 = W_res)
// into fragment-ordered bf16 Bf (frag f = kc*16+colhi; lane l: col_lo=l&15,
// ksub=l>>4; 8 bf16 each). Block 32 computes per-channel constants Ws/Cd.
// ---------------------------------------------------------------------------
__global__ __launch_bounds__(256)
void pcg_prep(const float* __restrict__ W_lin,
              const float* __restrict__ W_res,
              const float* __restrict__ weight,
              const float* __restrict__ b_lin,
              const float* __restrict__ bias,
              const float* __restrict__ b_res,
              ushort* __restrict__ Bf,
              float* __restrict__ Ws,
              float* __restrict__ Cd) {
    if (blockIdx.x == 32) {
        int d = threadIdx.x;
        if (d >= C_OUT) return;
        float freq = powf(10000.0f, -(float)(d & ~1) / (float)C_OUT);
        float ws = 0.f, p = 0.f;
        for (int s = 0; s < S_MB; ++s) {
            int idx = (int)floorf((float)s * (9.0f / 17.0f));
            ws += weight[d * KS + idx];
            float ang = (float)idx * freq;
            p += (d & 1) ? cosf(ang) : sinf(ang);
        }
        Ws[d] = ws;
        Cd[d] = ws * ((float)(K_NBR + 1) * b_lin[d] + p) + bias[d] + b_res[d];
        return;
    }
    const int tt     = blockIdx.x * 256 + threadIdx.x;   // 0..8191
    const int col_lo = tt & 15;
    const int ksub   = (tt >> 4) & 3;
    const int colhi  = (tt >> 6) & 15;
    const int kc     = tt >> 10;
    const int col    = colhi * 16 + col_lo;
    const int k0     = kc * 32 + ksub * 8;
    const float* Wr = (col < C_OUT)
        ? &W_lin[(size_t)col * C_IN + k0]
        : &W_res[(size_t)(col - C_OUT) * C_IN + k0];
    const f32x4 w0 = *reinterpret_cast<const f32x4*>(Wr);
    const f32x4 w1 = *reinterpret_cast<const f32x4*>(Wr + 4);
    ushort b[8] = { f2bf(w0.x), f2bf(w0.y), f2bf(w0.z), f2bf(w0.w),
                    f2bf(w1.x), f2bf(w1.y), f2bf(w1.z), f2bf(w1.w) };
    *reinterpret_cast<uint4*>(&Bf[(size_t)tt * 8]) =
        *reinterpret_cast<const uint4*>(b);
}

// ---------------------------------------------------------------------------
// MFMA GEMM + full epilogue fold:
//   Gs[n][d] = Ws[d] * (ndata[n,:].W_lin[d,:])            (bf16, gathered)
//   Pc[n][d] = Gs + ndata[n,:].W_res[d,:] + Cd[d]         (bf16, per-node part)
// Block: 64 rows x 256 stacked cols, 4 waves; wave w owns G cols w*32..+31
// (cg 0,1) and R cols of the SAME d (cg 2,3) so Gs/Pc combine in-register.
// A-tile staged f32->bf16 into LDS in fragment order with a 16B-granule XOR
// swizzle  u' = u ^ ksub ^ ((kc&1)<<2)  applied on BOTH write and read:
// spreads each wave's 64x16B accesses over all 32 banks (data-path floor).
// ---------------------------------------------------------------------------
__global__ __launch_bounds__(256)
void pcg_mfma(const float* __restrict__ ndata,
              const ushort* __restrict__ Bf,
              const float* __restrict__ Ws,
              const float* __restrict__ Cd,
              ushort* __restrict__ Gs,
              ushort* __restrict__ Pc) {
    __shared__ short sA[16384];                // 32 frags x 64 x 16B = 32 KB

    const int t  = threadIdx.x;
    const int n0 = blockIdx.x * 64;

    // ---- stage A tile: 8 x (two f32x4 -> one 16B ds_write_b128) ----
#pragma unroll
    for (int i = 0; i < 8; ++i) {
        const int v    = i * 256 + t;          // (row, kchunk) in 64 x 32
        const int row  = v >> 5;
        const int kch  = v & 31;
        f32x4 a0 = {0.f, 0.f, 0.f, 0.f}, a1 = {0.f, 0.f, 0.f, 0.f};
        if (n0 + row < N_NODES) {
            const float* p = &ndata[(size_t)(n0 + row) * C_IN + kch * 8];
            a0 = *reinterpret_cast<const f32x4*>(p);
            a1 = *reinterpret_cast<const f32x4*>(p + 4);
        }
        const int kc   = kch >> 2;
        const int ksub = kch & 3;
        const int f    = kc * 4 + (row >> 4);
        const int up   = (((row & 15) | (ksub << 4)) ^ ksub) ^ ((kc & 1) << 2);
        uint4 w;
        w.x = (uint)f2bf(a0.x) | ((uint)f2bf(a0.y) << 16);
        w.y = (uint)f2bf(a0.z) | ((uint)f2bf(a0.w) << 16);
        w.z = (uint)f2bf(a1.x) | ((uint)f2bf(a1.y) << 16);
        w.w = (uint)f2bf(a1.z) | ((uint)f2bf(a1.w) << 16);
        *reinterpret_cast<uint4*>(&sA[f * 512 + up * 8]) = w;
    }
    __syncthreads();

    const int wave = t >> 6;
    const int l    = t & 63;
    const int bu   = l ^ (l >> 4);             // base swizzled 16B-unit index

    // column-group -> stacked-column-high mapping (G,G,R,R for same d range)
    const int ch0 = 2 * wave;
    const int ch1 = 2 * wave + 1;
    const int ch2 = 8 + 2 * wave;
    const int ch3 = 9 + 2 * wave;

    f32x4 acc[4][4] = {};                       // [rg][cg]

#pragma unroll
    for (int kc = 0; kc < 8; ++kc) {
        const int ux = bu ^ ((kc & 1) << 2);
        bf16x8 a[4];
#pragma unroll
        for (int rg = 0; rg < 4; ++rg)
            a[rg] = *reinterpret_cast<const bf16x8*>(
                        &sA[(kc * 4 + rg) * 512 + ux * 8]);
        bf16x8 b[4];
        b[0] = *reinterpret_cast<const bf16x8*>(&Bf[((size_t)(kc * 16 + ch0) * 64 + l) * 8]);
        b[1] = *reinterpret_cast<const bf16x8*>(&Bf[((size_t)(kc * 16 + ch1) * 64 + l) * 8]);
        b[2] = *reinterpret_cast<const bf16x8*>(&Bf[((size_t)(kc * 16 + ch2) * 64 + l) * 8]);
        b[3] = *reinterpret_cast<const bf16x8*>(&Bf[((size_t)(kc * 16 + ch3) * 64 + l) * 8]);
#pragma unroll
        for (int rg = 0; rg < 4; ++rg)
#pragma unroll
            for (int cg = 0; cg < 4; ++cg)
                acc[rg][cg] = __builtin_amdgcn_mfma_f32_16x16x32_bf16(
                                  a[rg], b[cg], acc[rg][cg], 0, 0, 0);
    }

    // ---- epilogue: D layout col = lane&15, row = (lane>>4)*4 + reg ----
    const int cl  = l & 15;
    const int c0  = wave * 32 + cl;            // G col for cg 0 / R cg 2
    const int c1  = wave * 32 + 16 + cl;       // G col for cg 1 / R cg 3
    const float ws0 = Ws[c0], ws1 = Ws[c1];
    const float cd0 = Cd[c0], cd1 = Cd[c1];
    const int rl  = (l >> 4) * 4;
#pragma unroll
    for (int rg = 0; rg < 4; ++rg) {
#pragma unroll
        for (int j = 0; j < 4; ++j) {
            const int row = n0 + rg * 16 + rl + j;
            if (row < N_NODES) {
                const float gs0 = ws0 * acc[rg][0][j];
                const float gs1 = ws1 * acc[rg][1][j];
                Gs[(size_t)row * C_OUT + c0] = f2bf(gs0);
                Gs[(size_t)row * C_OUT + c1] = f2bf(gs1);
                Pc[(size_t)row * C_OUT + c0] = f2bf(gs0 + acc[rg][2][j] + cd0);
                Pc[(size_t)row * C_OUT + c1] = f2bf(gs1 + acc[rg][3][j] + cd1);
            }
        }
    }
}

// ---------------------------------------------------------------------------
// Gather: out[n][d] = Pc[n][d] + sum_k Gs[neighbors[n,k]][d]
// 4 nodes per 256-thread block; lane (64/node) covers cols 2l, 2l+1.
// ---------------------------------------------------------------------------
__global__ __launch_bounds__(256)
void pcg_gather(const int* __restrict__ neighbors,
                const ushort* __restrict__ Gs,
                const ushort* __restrict__ Pc,
                float* __restrict__ out) {
    __shared__ int snb[64];
    const int t = threadIdx.x;
    if (t < 64) snb[t] = neighbors[(size_t)blockIdx.x * 64 + t];
    __syncthreads();

    const int g = t >> 6;                      // node group 0..3
    const int l = t & 63;
    const int n = blockIdx.x * 4 + g;

    uint p = *reinterpret_cast<const uint*>(&Pc[(size_t)n * C_OUT + 2 * l]);
    float a0 = __builtin_bit_cast(float, p << 16);
    float a1 = __builtin_bit_cast(float, p & 0xffff0000u);

#pragma unroll
    for (int k = 0; k < K_NBR; ++k) {
        const int m = snb[g * 16 + k];
        uint v = *reinterpret_cast<const uint*>(&Gs[(size_t)m * C_OUT + 2 * l]);
        a0 += __builtin_bit_cast(float, v << 16);
        a1 += __builtin_bit_cast(float, v & 0xffff0000u);
    }

    f32x2 o = {a0, a1};
    *reinterpret_cast<f32x2*>(&out[(size_t)n * C_OUT + 2 * l]) = o;
}

// ---------------------------------------------------------------------------
extern "C" void kernel_launch(void* const* d_in, const int* in_sizes, int n_in,
                              void* d_out, int out_size, void* d_ws, size_t ws_size,
                              hipStream_t stream) {
    const float* ndata     = (const float*)d_in[0];
    const int*   neighbors = (const int*)  d_in[1];
    const float* W_lin     = (const float*)d_in[2];
    const float* b_lin     = (const float*)d_in[3];
    const float* weight    = (const float*)d_in[4];
    const float* bias      = (const float*)d_in[5];
    const float* W_res     = (const float*)d_in[6];
    const float* b_res     = (const float*)d_in[7];
    float* out = (float*)d_out;

    ushort* Bf = (ushort*)d_ws;                          // [8192][8] = 128 KB
    ushort* Gq = Bf + 65536;                             // Gs [N][128] = 7.68 MB
    ushort* Pq = Gq + (size_t)N_NODES * C_OUT;           // Pc [N][128] = 7.68 MB
    float*  Ws = (float*)(Pq + (size_t)N_NODES * C_OUT); // [128]
    float*  Cd = Ws + C_OUT;                             // [128]

    pcg_prep<<<33, 256, 0, stream>>>(W_lin, W_res, weight, b_lin, bias, b_res,
                                     Bf, Ws, Cd);
    pcg_mfma<<<(N_NODES + 63) / 64, 256, 0, stream>>>(ndata, Bf, Ws, Cd, Gq, Pq);
    pcg_gather<<<N_NODES / 4, 256, 0, stream>>>(neighbors, Gq, Pq, out);
}